// Round 2
// baseline (846.486 us; speedup 1.0000x reference)
//
#include <hip/hip_runtime.h>
#include <math.h>

#define T_TOK 2048
#define HD    2048
#define NEXP  64
#define KTOP  8
#define FD    768
#define CAPE  512

typedef float  f32x4 __attribute__((ext_vector_type(4)));
typedef __bf16 bf16x8 __attribute__((ext_vector_type(8)));
typedef __bf16 bf16x4 __attribute__((ext_vector_type(4)));

__device__ __forceinline__ void load_lds16(const void* g, void* l) {
  __builtin_amdgcn_global_load_lds(
      (const __attribute__((address_space(1))) unsigned int*)g,
      (__attribute__((address_space(3))) unsigned int*)l, 16, 0, 0);
}

// ---------------- Kernel 1: router (4 tokens per block) ----------------
__global__ __launch_bounds__(256) void router_kernel(
    const float* __restrict__ x, const float* __restrict__ rw,
    int* __restrict__ cnt, int* __restrict__ tok_list, float* __restrict__ w_list)
{
  const int t = threadIdx.x;
  const int tb = blockIdx.x * 4;
  __shared__ float xs[4][HD];
  __shared__ float lg[4][NEXP];

  const float4* xsrc = (const float4*)(x + (size_t)tb * HD);
  float4* xdst = (float4*)&xs[0][0];
  for (int i = t; i < 4 * HD / 4; i += 256) xdst[i] = xsrc[i];
  __syncthreads();

  {
    const int e = t >> 2, q = t & 3;
    const float* wrow = rw + (size_t)e * HD;
    float a0 = 0.f, a1 = 0.f, a2 = 0.f, a3 = 0.f;
    for (int i = 0; i < HD / 16; ++i) {
      int h = (i * 4 + q) * 4;
      float4 wv = *(const float4*)(wrow + h);
      float4 x0 = *(const float4*)&xs[0][h];
      float4 x1 = *(const float4*)&xs[1][h];
      float4 x2 = *(const float4*)&xs[2][h];
      float4 x3 = *(const float4*)&xs[3][h];
      a0 += wv.x*x0.x + wv.y*x0.y + wv.z*x0.z + wv.w*x0.w;
      a1 += wv.x*x1.x + wv.y*x1.y + wv.z*x1.z + wv.w*x1.w;
      a2 += wv.x*x2.x + wv.y*x2.y + wv.z*x2.z + wv.w*x2.w;
      a3 += wv.x*x3.x + wv.y*x3.y + wv.z*x3.z + wv.w*x3.w;
    }
    a0 += __shfl_xor(a0, 1); a0 += __shfl_xor(a0, 2);
    a1 += __shfl_xor(a1, 1); a1 += __shfl_xor(a1, 2);
    a2 += __shfl_xor(a2, 1); a2 += __shfl_xor(a2, 2);
    a3 += __shfl_xor(a3, 1); a3 += __shfl_xor(a3, 2);
    if (q == 0) { lg[0][e] = a0; lg[1][e] = a1; lg[2][e] = a2; lg[3][e] = a3; }
  }
  __syncthreads();

  const int wid = t >> 6, lane = t & 63;
  float v = lg[wid][lane];
  float mx = v;
  for (int o = 32; o; o >>= 1) mx = fmaxf(mx, __shfl_xor(mx, o));
  float p = expf(v - mx);
  float s = p;
  for (int o = 32; o; o >>= 1) s += __shfl_xor(s, o);
  float prob = p / s;

  float r = prob;
  float wk[KTOP]; int ik[KTOP]; float wsum = 0.f;
  #pragma unroll
  for (int k = 0; k < KTOP; ++k) {
    float bv = r; int bl = lane;
    for (int o = 32; o; o >>= 1) {
      float ov = __shfl_xor(bv, o); int ol = __shfl_xor(bl, o);
      if (ov > bv || (ov == bv && ol < bl)) { bv = ov; bl = ol; }
    }
    wk[k] = bv; ik[k] = bl; wsum += bv;
    if (lane == bl) r = -1.f;
  }
  if (lane == 0) {
    float inv = 1.f / (wsum + 1e-20f);
    int token = tb + wid;
    #pragma unroll
    for (int k = 0; k < KTOP; ++k) {
      int ex = ik[k];
      int pos = atomicAdd(&cnt[ex], 1);
      if (pos < CAPE) {
        tok_list[ex * CAPE + pos] = token;
        w_list[ex * CAPE + pos] = wk[k] * inv;
      }
    }
  }
}

// ---------------- Kernel 2: f32 -> bf16 convert of hidden_states ----------------
__global__ __launch_bounds__(256) void cvt_kernel(
    const float* __restrict__ x, unsigned short* __restrict__ xb)
{
  int i = blockIdx.x * 256 + threadIdx.x;   // exactly T*H/4 threads
  float4 v = ((const float4*)x)[i];
  bf16x4 o = { (__bf16)v.x, (__bf16)v.y, (__bf16)v.z, (__bf16)v.w };
  ((bf16x4*)xb)[i] = o;
}

// ---------------- Kernel 3: gate/up GEMM + SiLU -> hmid (bf16) ----------------
// 2-phase pipelined: A dbuf via global_load_lds, B dbuf via reg-stage + cvt_pk.
__global__ __launch_bounds__(256) void gateup_kernel(
    const unsigned short* __restrict__ xb,
    const float* __restrict__ wg, const float* __restrict__ wu,
    const int* __restrict__ cnt, const int* __restrict__ tok_list,
    unsigned short* __restrict__ hmid)
{
  const int nt = blockIdx.x, mt = blockIdx.y, e = blockIdx.z;
  int ne = cnt[e]; ne = ne < CAPE ? ne : CAPE;
  if (mt * 128 >= ne) return;
  const int t = threadIdx.x, lane = t & 63, wid = t >> 6;
  const int wr = wid >> 1, wc = wid & 1;

  __shared__ __align__(16) unsigned short A[2 * 128 * 64];   // 32 KB, XOR-swizzled granules
  __shared__ __align__(16) unsigned short Bg[2 * 64 * 72];   // 18.4 KB, [n][k] 144B stride
  __shared__ __align__(16) unsigned short Bu[2 * 64 * 72];
  __shared__ int toks[128];

  if (t < 128) {
    int r = mt * 128 + t;
    toks[t] = tok_list[e * CAPE + (r < ne ? r : 0)];
  }
  __syncthreads();

  f32x4 z4 = {0.f, 0.f, 0.f, 0.f};
  f32x4 gacc[4][2], uacc[4][2];
  #pragma unroll
  for (int i = 0; i < 4; ++i)
    #pragma unroll
    for (int j = 0; j < 2; ++j) { gacc[i][j] = z4; uacc[i][j] = z4; }

  const size_t wbase = (size_t)e * HD * FD + (size_t)nt * 64;
  const int nc = t & 15, kc = t >> 4;
  float4 rg0, rg1, rg2, rg3, ru0, ru1, ru2, ru3;

#define LOAD_B_GU(K0) do { \
    const float* pg = wg + wbase + (size_t)((K0) + kc * 4) * FD + nc * 4; \
    const float* pu = wu + wbase + (size_t)((K0) + kc * 4) * FD + nc * 4; \
    rg0 = *(const float4*)pg;          rg1 = *(const float4*)(pg + FD); \
    rg2 = *(const float4*)(pg + 2*FD); rg3 = *(const float4*)(pg + 3*FD); \
    ru0 = *(const float4*)pu;          ru1 = *(const float4*)(pu + FD); \
    ru2 = *(const float4*)(pu + 2*FD); ru3 = *(const float4*)(pu + 3*FD); \
  } while (0)

#define STAGE_A_GU(KT, BUF) do { \
    const int k0s = (KT) * 64; \
    _Pragma("unroll") \
    for (int i_ = 0; i_ < 4; ++i_) { \
      const int inst = wid * 4 + i_; \
      const int G = inst * 64 + lane; \
      const int m = G >> 3, gg = G & 7; \
      load_lds16(xb + (size_t)toks[m] * HD + k0s + 8 * (gg ^ (m & 7)), \
                 &A[(BUF) * 8192 + inst * 512]); \
    } \
  } while (0)

#define CVT_B(DST, BUF, r0, r1, r2, r3) do { \
    __bf16* bb = (__bf16*)&(DST)[(BUF) * 4608]; \
    *(bf16x4*)&bb[(nc*4+0)*72 + kc*4] = (bf16x4){(__bf16)r0.x,(__bf16)r1.x,(__bf16)r2.x,(__bf16)r3.x}; \
    *(bf16x4*)&bb[(nc*4+1)*72 + kc*4] = (bf16x4){(__bf16)r0.y,(__bf16)r1.y,(__bf16)r2.y,(__bf16)r3.y}; \
    *(bf16x4*)&bb[(nc*4+2)*72 + kc*4] = (bf16x4){(__bf16)r0.z,(__bf16)r1.z,(__bf16)r2.z,(__bf16)r3.z}; \
    *(bf16x4*)&bb[(nc*4+3)*72 + kc*4] = (bf16x4){(__bf16)r0.w,(__bf16)r1.w,(__bf16)r2.w,(__bf16)r3.w}; \
  } while (0)

  // prologue: stage tile 0
  LOAD_B_GU(0);
  STAGE_A_GU(0, 0);
  CVT_B(Bg, 0, rg0, rg1, rg2, rg3);
  CVT_B(Bu, 0, ru0, ru1, ru2, ru3);
  __syncthreads();

  for (int kt = 0; kt < HD / 64; ++kt) {
    const int cur = kt & 1;
    const bool more = (kt + 1) < HD / 64;
    if (more) {               // issue next-tile loads BEFORE compute
      LOAD_B_GU((kt + 1) * 64);
      STAGE_A_GU(kt + 1, cur ^ 1);
    }
    const char* Ab = (const char*)&A[cur * 8192];
    const unsigned short* BgB = &Bg[cur * 4608];
    const unsigned short* BuB = &Bu[cur * 4608];
    #pragma unroll
    for (int ks = 0; ks < 2; ++ks) {
      bf16x8 af[4];
      #pragma unroll
      for (int mf = 0; mf < 4; ++mf) {
        int row = wr * 64 + mf * 16 + (lane & 15);
        int byte = row * 128 + (lane >> 4) * 16 + ks * 64;
        byte ^= (row & 7) << 4;
        af[mf] = *(const bf16x8*)(Ab + byte);
      }
      #pragma unroll
      for (int nf = 0; nf < 2; ++nf) {
        int n = wc * 32 + nf * 16 + (lane & 15);
        int off = n * 72 + (lane >> 4) * 8 + ks * 32;
        bf16x8 bgf = *(const bf16x8*)&BgB[off];
        bf16x8 bum = *(const bf16x8*)&BuB[off];
        #pragma unroll
        for (int mf = 0; mf < 4; ++mf) {
          gacc[mf][nf] = __builtin_amdgcn_mfma_f32_16x16x32_bf16(af[mf], bgf, gacc[mf][nf], 0, 0, 0);
          uacc[mf][nf] = __builtin_amdgcn_mfma_f32_16x16x32_bf16(af[mf], bum, uacc[mf][nf], 0, 0, 0);
        }
      }
    }
    if (more) {               // convert+write next tile after compute
      CVT_B(Bg, cur ^ 1, rg0, rg1, rg2, rg3);
      CVT_B(Bu, cur ^ 1, ru0, ru1, ru2, ru3);
    }
    __syncthreads();
  }
#undef LOAD_B_GU
#undef STAGE_A_GU

  // epilogue: hmid = silu(g)*u   (D layout: col=lane&15, row=4*(lane>>4)+reg)
  const size_t hbase = (size_t)e * CAPE + (size_t)mt * 128;
  __bf16* hm = (__bf16*)hmid;
  #pragma unroll
  for (int mf = 0; mf < 4; ++mf) {
    #pragma unroll
    for (int nf = 0; nf < 2; ++nf) {
      #pragma unroll
      for (int r = 0; r < 4; ++r) {
        int row = wr * 64 + mf * 16 + (lane >> 4) * 4 + r;
        int c = nt * 64 + wc * 32 + nf * 16 + (lane & 15);
        float gv = gacc[mf][nf][r], uv = uacc[mf][nf][r];
        float hv = gv / (1.f + __expf(-gv)) * uv;
        hm[(hbase + row) * FD + c] = (__bf16)hv;
      }
    }
  }
}

// ---------------- Kernel 4: down GEMM + weighted scatter-add ----------------
__global__ __launch_bounds__(256) void down_kernel(
    const unsigned short* __restrict__ hmid,
    const float* __restrict__ wd,
    const int* __restrict__ cnt, const int* __restrict__ tok_list,
    const float* __restrict__ w_list, float* __restrict__ out)
{
  const int nt = blockIdx.x, mt = blockIdx.y, e = blockIdx.z;
  int ne = cnt[e]; ne = ne < CAPE ? ne : CAPE;
  if (mt * 128 >= ne) return;
  const int t = threadIdx.x, lane = t & 63, wid = t >> 6;
  const int wr = wid >> 1, wc = wid & 1;

  __shared__ __align__(16) unsigned short A[2 * 128 * 64];
  __shared__ __align__(16) unsigned short Bd[2 * 64 * 72];
  __shared__ int toks[128];
  __shared__ float wts[128];

  if (t < 128) {
    int r = mt * 128 + t;
    bool vv = r < ne;
    toks[t] = vv ? tok_list[e * CAPE + r] : 0;
    wts[t]  = vv ? w_list[e * CAPE + r] : 0.f;
  }
  __syncthreads();

  f32x4 z4 = {0.f, 0.f, 0.f, 0.f};
  f32x4 dacc[4][2];
  #pragma unroll
  for (int i = 0; i < 4; ++i)
    #pragma unroll
    for (int j = 0; j < 2; ++j) dacc[i][j] = z4;

  const size_t wbase = (size_t)e * FD * HD + (size_t)nt * 64;
  const size_t arow = (size_t)e * CAPE + (size_t)mt * 128;
  const int nc = t & 15, kc = t >> 4;
  float4 rd0, rd1, rd2, rd3;

#define LOAD_B_D(K0) do { \
    const float* pd = wd + wbase + (size_t)((K0) + kc * 4) * HD + nc * 4; \
    rd0 = *(const float4*)pd;          rd1 = *(const float4*)(pd + HD); \
    rd2 = *(const float4*)(pd + 2*HD); rd3 = *(const float4*)(pd + 3*HD); \
  } while (0)

#define STAGE_A_D(KT, BUF) do { \
    const int k0s = (KT) * 64; \
    _Pragma("unroll") \
    for (int i_ = 0; i_ < 4; ++i_) { \
      const int inst = wid * 4 + i_; \
      const int G = inst * 64 + lane; \
      const int m = G >> 3, gg = G & 7; \
      load_lds16(hmid + (arow + m) * FD + k0s + 8 * (gg ^ (m & 7)), \
                 &A[(BUF) * 8192 + inst * 512]); \
    } \
  } while (0)

  LOAD_B_D(0);
  STAGE_A_D(0, 0);
  CVT_B(Bd, 0, rd0, rd1, rd2, rd3);
  __syncthreads();

  for (int kt = 0; kt < FD / 64; ++kt) {
    const int cur = kt & 1;
    const bool more = (kt + 1) < FD / 64;
    if (more) {
      LOAD_B_D((kt + 1) * 64);
      STAGE_A_D(kt + 1, cur ^ 1);
    }
    const char* Ab = (const char*)&A[cur * 8192];
    const unsigned short* BdB = &Bd[cur * 4608];
    #pragma unroll
    for (int ks = 0; ks < 2; ++ks) {
      bf16x8 af[4];
      #pragma unroll
      for (int mf = 0; mf < 4; ++mf) {
        int row = wr * 64 + mf * 16 + (lane & 15);
        int byte = row * 128 + (lane >> 4) * 16 + ks * 64;
        byte ^= (row & 7) << 4;
        af[mf] = *(const bf16x8*)(Ab + byte);
      }
      #pragma unroll
      for (int nf = 0; nf < 2; ++nf) {
        int n = wc * 32 + nf * 16 + (lane & 15);
        int off = n * 72 + (lane >> 4) * 8 + ks * 32;
        bf16x8 bdf = *(const bf16x8*)&BdB[off];
        #pragma unroll
        for (int mf = 0; mf < 4; ++mf)
          dacc[mf][nf] = __builtin_amdgcn_mfma_f32_16x16x32_bf16(af[mf], bdf, dacc[mf][nf], 0, 0, 0);
      }
    }
    if (more) CVT_B(Bd, cur ^ 1, rd0, rd1, rd2, rd3);
    __syncthreads();
  }
#undef LOAD_B_D
#undef STAGE_A_D
#undef CVT_B

  // epilogue: weighted atomic scatter-add
  #pragma unroll
  for (int mf = 0; mf < 4; ++mf) {
    #pragma unroll
    for (int nf = 0; nf < 2; ++nf) {
      int c = nt * 64 + wc * 32 + nf * 16 + (lane & 15);
      #pragma unroll
      for (int r = 0; r < 4; ++r) {
        int row = wr * 64 + mf * 16 + (lane >> 4) * 4 + r;
        if (mt * 128 + row < ne) {
          int tok = toks[row];
          float w = wts[row];
          atomicAdd(&out[(size_t)tok * HD + c], w * dacc[mf][nf][r]);
        }
      }
    }
  }
}

extern "C" void kernel_launch(void* const* d_in, const int* in_sizes, int n_in,
                              void* d_out, int out_size, void* d_ws, size_t ws_size,
                              hipStream_t stream) {
  const float* x  = (const float*)d_in[0];
  const float* rw = (const float*)d_in[1];
  const float* wg = (const float*)d_in[2];
  const float* wu = (const float*)d_in[3];
  const float* wd = (const float*)d_in[4];
  float* out = (float*)d_out;

  char* ws = (char*)d_ws;
  unsigned short* xb   = (unsigned short*)ws;            // 8,388,608 B
  int* cnt             = (int*)(ws + 8388608);           // 256 B
  int* tok_list        = (int*)(ws + 8388864);           // 131,072 B
  float* w_list        = (float*)(ws + 8519936);         // 131,072 B
  unsigned short* hmid = (unsigned short*)(ws + 8651008);// 50,331,648 B

  hipMemsetAsync(d_out, 0, (size_t)out_size * sizeof(float), stream);
  hipMemsetAsync(cnt, 0, NEXP * sizeof(int), stream);

  router_kernel<<<T_TOK / 4, 256, 0, stream>>>(x, rw, cnt, tok_list, w_list);
  cvt_kernel<<<(T_TOK * HD / 4) / 256, 256, 0, stream>>>(x, xb);
  gateup_kernel<<<dim3(FD / 64, CAPE / 128, NEXP), 256, 0, stream>>>(xb, wg, wu, cnt, tok_list, hmid);
  down_kernel<<<dim3(HD / 64, CAPE / 128, NEXP), 256, 0, stream>>>(hmid, wd, cnt, tok_list, w_list, out);
}

// Round 3
// 654.177 us; speedup vs baseline: 1.2940x; 1.2940x over previous
//
#include <hip/hip_runtime.h>
#include <math.h>

#define T_TOK 2048
#define HD    2048
#define NEXP  64
#define KTOP  8
#define FD    768
#define CAPE  512

typedef float  f32x4 __attribute__((ext_vector_type(4)));
typedef __bf16 bf16x8 __attribute__((ext_vector_type(8)));
typedef __bf16 bf16x4 __attribute__((ext_vector_type(4)));

__device__ __forceinline__ void load_lds16(const void* g, void* l) {
  __builtin_amdgcn_global_load_lds(
      (const __attribute__((address_space(1))) unsigned int*)g,
      (__attribute__((address_space(3))) unsigned int*)l, 16, 0, 0);
}

#define WAITCNT(S) asm volatile(S ::: "memory")
#define BARRIER()  __builtin_amdgcn_s_barrier()

// ---------------- Kernel 1: router (4 tokens per block) ----------------
__global__ __launch_bounds__(256) void router_kernel(
    const float* __restrict__ x, const float* __restrict__ rw,
    int* __restrict__ cnt, int* __restrict__ tok_list, float* __restrict__ w_list)
{
  const int t = threadIdx.x;
  const int tb = blockIdx.x * 4;
  __shared__ float xs[4][HD];
  __shared__ float lg[4][NEXP];

  const float4* xsrc = (const float4*)(x + (size_t)tb * HD);
  float4* xdst = (float4*)&xs[0][0];
  for (int i = t; i < 4 * HD / 4; i += 256) xdst[i] = xsrc[i];
  __syncthreads();

  {
    const int e = t >> 2, q = t & 3;
    const float* wrow = rw + (size_t)e * HD;
    float a0 = 0.f, a1 = 0.f, a2 = 0.f, a3 = 0.f;
    for (int i = 0; i < HD / 16; ++i) {
      int h = (i * 4 + q) * 4;
      float4 wv = *(const float4*)(wrow + h);
      float4 x0 = *(const float4*)&xs[0][h];
      float4 x1 = *(const float4*)&xs[1][h];
      float4 x2 = *(const float4*)&xs[2][h];
      float4 x3 = *(const float4*)&xs[3][h];
      a0 += wv.x*x0.x + wv.y*x0.y + wv.z*x0.z + wv.w*x0.w;
      a1 += wv.x*x1.x + wv.y*x1.y + wv.z*x1.z + wv.w*x1.w;
      a2 += wv.x*x2.x + wv.y*x2.y + wv.z*x2.z + wv.w*x2.w;
      a3 += wv.x*x3.x + wv.y*x3.y + wv.z*x3.z + wv.w*x3.w;
    }
    a0 += __shfl_xor(a0, 1); a0 += __shfl_xor(a0, 2);
    a1 += __shfl_xor(a1, 1); a1 += __shfl_xor(a1, 2);
    a2 += __shfl_xor(a2, 1); a2 += __shfl_xor(a2, 2);
    a3 += __shfl_xor(a3, 1); a3 += __shfl_xor(a3, 2);
    if (q == 0) { lg[0][e] = a0; lg[1][e] = a1; lg[2][e] = a2; lg[3][e] = a3; }
  }
  __syncthreads();

  const int wid = t >> 6, lane = t & 63;
  float v = lg[wid][lane];
  float mx = v;
  for (int o = 32; o; o >>= 1) mx = fmaxf(mx, __shfl_xor(mx, o));
  float p = expf(v - mx);
  float s = p;
  for (int o = 32; o; o >>= 1) s += __shfl_xor(s, o);
  float prob = p / s;

  float r = prob;
  float wk[KTOP]; int ik[KTOP]; float wsum = 0.f;
  #pragma unroll
  for (int k = 0; k < KTOP; ++k) {
    float bv = r; int bl = lane;
    for (int o = 32; o; o >>= 1) {
      float ov = __shfl_xor(bv, o); int ol = __shfl_xor(bl, o);
      if (ov > bv || (ov == bv && ol < bl)) { bv = ov; bl = ol; }
    }
    wk[k] = bv; ik[k] = bl; wsum += bv;
    if (lane == bl) r = -1.f;
  }
  if (lane == 0) {
    float inv = 1.f / (wsum + 1e-20f);
    int token = tb + wid;
    #pragma unroll
    for (int k = 0; k < KTOP; ++k) {
      int ex = ik[k];
      int pos = atomicAdd(&cnt[ex], 1);
      if (pos < CAPE) {
        tok_list[ex * CAPE + pos] = token;
        w_list[ex * CAPE + pos] = wk[k] * inv;
      }
    }
  }
}

// ---------------- Kernel 2: f32 -> bf16 convert of hidden_states ----------------
__global__ __launch_bounds__(256) void cvt_kernel(
    const float* __restrict__ x, unsigned short* __restrict__ xb)
{
  int i = blockIdx.x * 256 + threadIdx.x;   // exactly T*H/4 threads
  f32x4 v = ((const f32x4*)x)[i];
  bf16x4 o = { (__bf16)v[0], (__bf16)v[1], (__bf16)v[2], (__bf16)v[3] };
  ((bf16x4*)xb)[i] = o;
}

// ============ shared GEMM building blocks (macros use local names) ============
// B LDS layout: [n][k], row stride 72 shorts (144B), XOR swizzle ((n>>2)&7)<<3
// (short units, 16B granule). Writes 2-way (free), reads <=3-way.
// A LDS layout: [m][k] linear granules, source pre-swizzled, XOR ((row&7)<<4) bytes.

// ---------------- Kernel 3: gate/up GEMM + SiLU -> hmid (bf16) ----------------
__global__ __launch_bounds__(256, 2) void gateup_kernel(
    const unsigned short* __restrict__ xb,
    const float* __restrict__ wg, const float* __restrict__ wu,
    const int* __restrict__ cnt, const int* __restrict__ tok_list,
    unsigned short* __restrict__ hmid)
{
  const int nt = blockIdx.x, mt = blockIdx.y, e = blockIdx.z;
  int ne = cnt[e]; ne = ne < CAPE ? ne : CAPE;
  if (mt * 128 >= ne) return;
  const int t = threadIdx.x, lane = t & 63, wid = t >> 6;
  const int wr = wid >> 1, wc = wid & 1;

  __shared__ __align__(16) unsigned short A[2 * 128 * 64];   // 32 KB
  __shared__ __align__(16) unsigned short Bg[2 * 64 * 72];   // 18 KB
  __shared__ __align__(16) unsigned short Bu[2 * 64 * 72];
  __shared__ int toks[128];

  if (t < 128) {
    int r = mt * 128 + t;
    toks[t] = tok_list[e * CAPE + (r < ne ? r : 0)];
  }
  __syncthreads();

  // hoist per-lane A source bases (loop-invariant)
  const unsigned short* asrc[4];
  #pragma unroll
  for (int i = 0; i < 4; ++i) {
    const int inst = wid * 4 + i;
    const int G = inst * 64 + lane;
    const int m = G >> 3, gg = G & 7;
    asrc[i] = xb + (size_t)toks[m] * HD + 8 * (gg ^ (m & 7));
  }

  f32x4 z4 = {0.f, 0.f, 0.f, 0.f};
  f32x4 gacc[4][2], uacc[4][2];
  #pragma unroll
  for (int i = 0; i < 4; ++i)
    #pragma unroll
    for (int j = 0; j < 2; ++j) { gacc[i][j] = z4; uacc[i][j] = z4; }

  const size_t wbase = (size_t)e * HD * FD + (size_t)nt * 64;
  const int nc = t & 15, kc = t >> 4;
  f32x4 Ra[8], Rb[8];

#define LOAD_GU(K0, R) do { \
    const float* pg_ = wg + wbase + (size_t)((K0) + kc * 4) * FD + nc * 4; \
    const float* pu_ = wu + wbase + (size_t)((K0) + kc * 4) * FD + nc * 4; \
    R[0] = *(const f32x4*)pg_;            R[1] = *(const f32x4*)(pg_ + FD); \
    R[2] = *(const f32x4*)(pg_ + 2*FD);   R[3] = *(const f32x4*)(pg_ + 3*FD); \
    R[4] = *(const f32x4*)pu_;            R[5] = *(const f32x4*)(pu_ + FD); \
    R[6] = *(const f32x4*)(pu_ + 2*FD);   R[7] = *(const f32x4*)(pu_ + 3*FD); \
  } while (0)

#define STAGE_A4(KT, BUF) do { \
    const int k0s_ = (KT) * 64; \
    _Pragma("unroll") \
    for (int i_ = 0; i_ < 4; ++i_) \
      load_lds16(asrc[i_] + k0s_, &A[(BUF) * 8192 + (wid * 4 + i_) * 512]); \
  } while (0)

#define CVT_GU(BUF, R) do { \
    __bf16* bg_ = (__bf16*)&Bg[(BUF) * 4608]; \
    __bf16* bu_ = (__bf16*)&Bu[(BUF) * 4608]; \
    const int xm_ = (nc & 7) << 3; \
    _Pragma("unroll") \
    for (int j_ = 0; j_ < 4; ++j_) { \
      int so_ = (nc * 4 + j_) * 72 + ((kc * 4) ^ xm_); \
      *(bf16x4*)&bg_[so_] = (bf16x4){(__bf16)R[0][j_], (__bf16)R[1][j_], (__bf16)R[2][j_], (__bf16)R[3][j_]}; \
      *(bf16x4*)&bu_[so_] = (bf16x4){(__bf16)R[4][j_], (__bf16)R[5][j_], (__bf16)R[6][j_], (__bf16)R[7][j_]}; \
    } \
  } while (0)

#define COMPUTE_GU(CUR) do { \
    const char* Ab_ = (const char*)&A[(CUR) * 8192]; \
    const __bf16* Bg_ = (const __bf16*)&Bg[(CUR) * 4608]; \
    const __bf16* Bu_ = (const __bf16*)&Bu[(CUR) * 4608]; \
    _Pragma("unroll") \
    for (int ks = 0; ks < 2; ++ks) { \
      bf16x8 af[4]; \
      _Pragma("unroll") \
      for (int mf = 0; mf < 4; ++mf) { \
        int row = wr * 64 + mf * 16 + (lane & 15); \
        int byte = row * 128 + (lane >> 4) * 16 + ks * 64; \
        byte ^= (row & 7) << 4; \
        af[mf] = *(const bf16x8*)(Ab_ + byte); \
      } \
      _Pragma("unroll") \
      for (int nf = 0; nf < 2; ++nf) { \
        int n = wc * 32 + nf * 16 + (lane & 15); \
        int so = n * 72 + ((((lane >> 4) * 8) + ks * 32) ^ (((n >> 2) & 7) << 3)); \
        bf16x8 bgf = *(const bf16x8*)&Bg_[so]; \
        bf16x8 bum = *(const bf16x8*)&Bu_[so]; \
        _Pragma("unroll") \
        for (int mf = 0; mf < 4; ++mf) { \
          gacc[mf][nf] = __builtin_amdgcn_mfma_f32_16x16x32_bf16(af[mf], bgf, gacc[mf][nf], 0, 0, 0); \
          uacc[mf][nf] = __builtin_amdgcn_mfma_f32_16x16x32_bf16(af[mf], bum, uacc[mf][nf], 0, 0, 0); \
        } \
      } \
    } \
  } while (0)

  // prologue: tiles 0,1
  LOAD_GU(0, Ra);          // 8 vm
  STAGE_A4(0, 0);          // +4
  LOAD_GU(64, Rb);         // +8 -> 20
  WAITCNT("s_waitcnt vmcnt(12)");            // Ra done
  CVT_GU(0, Ra);
  WAITCNT("s_waitcnt vmcnt(8) lgkmcnt(0)");  // A(0) done; Rb in flight
  BARRIER();

  // main: 15 double-steps, kt = 0..29; loads tiles up to 31
  for (int i = 0; i < 15; ++i) {
    const int kt = 2 * i;
    STAGE_A4(kt + 1, 1);
    LOAD_GU((kt + 2) * 64, Ra);
    WAITCNT("s_waitcnt vmcnt(12)");            // Rb ready
    CVT_GU(1, Rb);
    COMPUTE_GU(0);
    WAITCNT("s_waitcnt vmcnt(8) lgkmcnt(0)");  // A(kt+1) done; Ra flies
    BARRIER();

    STAGE_A4(kt + 2, 0);
    LOAD_GU((kt + 3) * 64, Rb);
    WAITCNT("s_waitcnt vmcnt(12)");            // Ra ready
    CVT_GU(0, Ra);
    COMPUTE_GU(1);
    WAITCNT("s_waitcnt vmcnt(8) lgkmcnt(0)");  // A(kt+2) done; Rb flies
    BARRIER();
  }
  // tail: kt=30 (stage 31, no load), kt=31
  STAGE_A4(31, 1);
  CVT_GU(1, Rb);                               // compiler inserts reg-dep wait
  COMPUTE_GU(0);
  WAITCNT("s_waitcnt vmcnt(0) lgkmcnt(0)");
  BARRIER();
  COMPUTE_GU(1);

#undef LOAD_GU
#undef STAGE_A4
#undef CVT_GU
#undef COMPUTE_GU

  // epilogue: hmid = silu(g)*u   (D layout: col=lane&15, row=4*(lane>>4)+reg)
  const size_t hbase = (size_t)e * CAPE + (size_t)mt * 128;
  __bf16* hm = (__bf16*)hmid;
  #pragma unroll
  for (int mf = 0; mf < 4; ++mf) {
    #pragma unroll
    for (int nf = 0; nf < 2; ++nf) {
      #pragma unroll
      for (int r = 0; r < 4; ++r) {
        int row = wr * 64 + mf * 16 + (lane >> 4) * 4 + r;
        int c = nt * 64 + wc * 32 + nf * 16 + (lane & 15);
        float gv = gacc[mf][nf][r], uv = uacc[mf][nf][r];
        float hv = gv / (1.f + __expf(-gv)) * uv;
        hm[(hbase + row) * FD + c] = (__bf16)hv;
      }
    }
  }
}

// ---------------- Kernel 4: down GEMM + weighted scatter-add ----------------
__global__ __launch_bounds__(256, 2) void down_kernel(
    const unsigned short* __restrict__ hmid,
    const float* __restrict__ wd,
    const int* __restrict__ cnt, const int* __restrict__ tok_list,
    const float* __restrict__ w_list, float* __restrict__ out)
{
  const int nt = blockIdx.x, mt = blockIdx.y, e = blockIdx.z;
  int ne = cnt[e]; ne = ne < CAPE ? ne : CAPE;
  if (mt * 128 >= ne) return;
  const int t = threadIdx.x, lane = t & 63, wid = t >> 6;
  const int wr = wid >> 1, wc = wid & 1;

  __shared__ __align__(16) unsigned short A[2 * 128 * 64];
  __shared__ __align__(16) unsigned short Bd[2 * 64 * 72];
  __shared__ int toks[128];
  __shared__ float wts[128];

  if (t < 128) {
    int r = mt * 128 + t;
    bool vv = r < ne;
    toks[t] = vv ? tok_list[e * CAPE + r] : 0;
    wts[t]  = vv ? w_list[e * CAPE + r] : 0.f;
  }
  __syncthreads();

  const size_t arow = (size_t)e * CAPE + (size_t)mt * 128;
  const unsigned short* asrc[4];
  #pragma unroll
  for (int i = 0; i < 4; ++i) {
    const int inst = wid * 4 + i;
    const int G = inst * 64 + lane;
    const int m = G >> 3, gg = G & 7;
    asrc[i] = hmid + (arow + m) * FD + 8 * (gg ^ (m & 7));
  }

  f32x4 z4 = {0.f, 0.f, 0.f, 0.f};
  f32x4 dacc[4][2];
  #pragma unroll
  for (int i = 0; i < 4; ++i)
    #pragma unroll
    for (int j = 0; j < 2; ++j) dacc[i][j] = z4;

  const size_t wbase = (size_t)e * FD * HD + (size_t)nt * 64;
  const int nc = t & 15, kc = t >> 4;
  f32x4 Ra[4], Rb[4];

#define LOAD_D(K0, R) do { \
    const float* pd_ = wd + wbase + (size_t)((K0) + kc * 4) * HD + nc * 4; \
    R[0] = *(const f32x4*)pd_;            R[1] = *(const f32x4*)(pd_ + HD); \
    R[2] = *(const f32x4*)(pd_ + 2*HD);   R[3] = *(const f32x4*)(pd_ + 3*HD); \
  } while (0)

#define STAGE_A4(KT, BUF) do { \
    const int k0s_ = (KT) * 64; \
    _Pragma("unroll") \
    for (int i_ = 0; i_ < 4; ++i_) \
      load_lds16(asrc[i_] + k0s_, &A[(BUF) * 8192 + (wid * 4 + i_) * 512]); \
  } while (0)

#define CVT_D(BUF, R) do { \
    __bf16* bd_ = (__bf16*)&Bd[(BUF) * 4608]; \
    const int xm_ = (nc & 7) << 3; \
    _Pragma("unroll") \
    for (int j_ = 0; j_ < 4; ++j_) { \
      int so_ = (nc * 4 + j_) * 72 + ((kc * 4) ^ xm_); \
      *(bf16x4*)&bd_[so_] = (bf16x4){(__bf16)R[0][j_], (__bf16)R[1][j_], (__bf16)R[2][j_], (__bf16)R[3][j_]}; \
    } \
  } while (0)

#define COMPUTE_D(CUR) do { \
    const char* Ab_ = (const char*)&A[(CUR) * 8192]; \
    const __bf16* Bd_ = (const __bf16*)&Bd[(CUR) * 4608]; \
    _Pragma("unroll") \
    for (int ks = 0; ks < 2; ++ks) { \
      bf16x8 af[4]; \
      _Pragma("unroll") \
      for (int mf = 0; mf < 4; ++mf) { \
        int row = wr * 64 + mf * 16 + (lane & 15); \
        int byte = row * 128 + (lane >> 4) * 16 + ks * 64; \
        byte ^= (row & 7) << 4; \
        af[mf] = *(const bf16x8*)(Ab_ + byte); \
      } \
      _Pragma("unroll") \
      for (int nf = 0; nf < 2; ++nf) { \
        int n = wc * 32 + nf * 16 + (lane & 15); \
        int so = n * 72 + ((((lane >> 4) * 8) + ks * 32) ^ (((n >> 2) & 7) << 3)); \
        bf16x8 bdf = *(const bf16x8*)&Bd_[so]; \
        _Pragma("unroll") \
        for (int mf = 0; mf < 4; ++mf) \
          dacc[mf][nf] = __builtin_amdgcn_mfma_f32_16x16x32_bf16(af[mf], bdf, dacc[mf][nf], 0, 0, 0); \
      } \
    } \
  } while (0)

  // prologue: tiles 0,1
  LOAD_D(0, Ra);           // 4 vm
  STAGE_A4(0, 0);          // +4
  LOAD_D(64, Rb);          // +4 -> 12
  WAITCNT("s_waitcnt vmcnt(8)");             // Ra done
  CVT_D(0, Ra);
  WAITCNT("s_waitcnt vmcnt(4) lgkmcnt(0)");  // A(0) done; Rb flies
  BARRIER();

  // main: 5 double-steps, kt = 0..9; loads tiles up to 11
  for (int i = 0; i < 5; ++i) {
    const int kt = 2 * i;
    STAGE_A4(kt + 1, 1);
    LOAD_D((kt + 2) * 64, Ra);
    WAITCNT("s_waitcnt vmcnt(8)");
    CVT_D(1, Rb);
    COMPUTE_D(0);
    WAITCNT("s_waitcnt vmcnt(4) lgkmcnt(0)");
    BARRIER();

    STAGE_A4(kt + 2, 0);
    LOAD_D((kt + 3) * 64, Rb);
    WAITCNT("s_waitcnt vmcnt(8)");
    CVT_D(0, Ra);
    COMPUTE_D(1);
    WAITCNT("s_waitcnt vmcnt(4) lgkmcnt(0)");
    BARRIER();
  }
  // tail: kt=10, kt=11
  STAGE_A4(11, 1);
  CVT_D(1, Rb);
  COMPUTE_D(0);
  WAITCNT("s_waitcnt vmcnt(0) lgkmcnt(0)");
  BARRIER();
  COMPUTE_D(1);

#undef LOAD_D
#undef STAGE_A4
#undef CVT_D
#undef COMPUTE_D

  // epilogue: weighted atomic scatter-add
  #pragma unroll
  for (int mf = 0; mf < 4; ++mf) {
    #pragma unroll
    for (int nf = 0; nf < 2; ++nf) {
      int c = nt * 64 + wc * 32 + nf * 16 + (lane & 15);
      #pragma unroll
      for (int r = 0; r < 4; ++r) {
        int row = wr * 64 + mf * 16 + (lane >> 4) * 4 + r;
        if (mt * 128 + row < ne) {
          int tok = toks[row];
          float w = wts[row];
          atomicAdd(&out[(size_t)tok * HD + c], w * dacc[mf][nf][r]);
        }
      }
    }
  }
}

extern "C" void kernel_launch(void* const* d_in, const int* in_sizes, int n_in,
                              void* d_out, int out_size, void* d_ws, size_t ws_size,
                              hipStream_t stream) {
  const float* x  = (const float*)d_in[0];
  const float* rw = (const float*)d_in[1];
  const float* wg = (const float*)d_in[2];
  const float* wu = (const float*)d_in[3];
  const float* wd = (const float*)d_in[4];
  float* out = (float*)d_out;

  char* ws = (char*)d_ws;
  unsigned short* xb   = (unsigned short*)ws;            // 8,388,608 B
  int* cnt             = (int*)(ws + 8388608);           // 256 B
  int* tok_list        = (int*)(ws + 8388864);           // 131,072 B
  float* w_list        = (float*)(ws + 8519936);         // 131,072 B
  unsigned short* hmid = (unsigned short*)(ws + 8651008);// 50,331,648 B

  hipMemsetAsync(d_out, 0, (size_t)out_size * sizeof(float), stream);
  hipMemsetAsync(cnt, 0, NEXP * sizeof(int), stream);

  router_kernel<<<T_TOK / 4, 256, 0, stream>>>(x, rw, cnt, tok_list, w_list);
  cvt_kernel<<<(T_TOK * HD / 4) / 256, 256, 0, stream>>>(x, xb);
  gateup_kernel<<<dim3(FD / 64, CAPE / 128, NEXP), 256, 0, stream>>>(xb, wg, wu, cnt, tok_list, hmid);
  down_kernel<<<dim3(HD / 64, CAPE / 128, NEXP), 256, 0, stream>>>(hmid, wd, cnt, tok_list, w_list, out);
}